// Round 4
// baseline (399.981 us; speedup 1.0000x reference)
//
#include <hip/hip_runtime.h>

#define NL 64
#define SQ 512
#define BATCH 1024
#define RING 8
#define DEPTH 6    // prefetch distance in steps; vmcnt wait = 4*(DEPTH-1) = 20

typedef _Float16 h8    __attribute__((ext_vector_type(8)));
typedef float    f32x4 __attribute__((ext_vector_type(4)));
typedef int      i32x4 __attribute__((ext_vector_type(4)));

#define EXP2F(x)  __builtin_amdgcn_exp2f(x)   // 2^x (v_exp_f32)
#define LOG2F(x)  __builtin_amdgcn_logf(x)    // log2 (v_log_f32)
#define MFMA16(a,b,c) __builtin_amdgcn_mfma_f32_16x16x32_f16((a),(b),(c),0,0,0)

static __device__ __forceinline__ int pkf16(float a, float b) {
    return __builtin_bit_cast(int, __builtin_amdgcn_cvt_pkrtz(a, b));
}

// async global->LDS, 16B per lane. LDS dest is the WAVE-UNIFORM slot base;
// HW scatters lane l to base + l*16. Global src is per-lane (gather OK).
static __device__ __forceinline__ void gl_lds16(const float* g, float* l) {
    __builtin_amdgcn_global_load_lds(
        (const __attribute__((address_space(1))) unsigned int*)g,
        (__attribute__((address_space(3))) unsigned int*)l, 16, 0, 0);
}

// Round-10: round-9 MFMA step math (verified correct) + LDS-ring emission
// pipeline. Round-9 failed on memory: register double-buffer of gathered
// emissions needed 128 VGPRs, compiler (VGPR=88) sank loads to point-of-use
// -> ~1000 cyc exposed gather latency per step (VALUBusy 4.6%, Occ 1.3%).
// Fix: 8-slot LDS ring filled by global_load_lds issued DEPTH=6 steps ahead
// (in-flight data lives in the VMEM queue + LDS, not VGPRs), counted
// s_waitcnt vmcnt(20) + sched_barrier(0) fencing (compiler cannot see the
// gload_lds -> ds_read dependency). Per-lane global src is arranged so lane
// l's 16B IS its own D-fragment: ds_read_b128 at [slot][m][l] needs no
// transpose and is conflict-free. E-frags prefetched 1 step ahead into regs;
// masks staged once into padded LDS [16][260] (2-way conflict = free).
__global__ __launch_bounds__(64, 1) void crf_scan_mfma(
    const float* __restrict__ emissions,   // [B, S, L]
    const int*   __restrict__ mask,        // [B, S]
    const float* __restrict__ trans,       // [L, L]
    const float* __restrict__ start_t,     // [L]
    const float* __restrict__ end_t,       // [L]
    float* __restrict__ ws_p,              // [2B][64]
    float* __restrict__ ws_c)              // [2B]  (log2-domain offsets)
{
    const int  blk   = blockIdx.x;         // 0..127
    const bool fwd   = blk < 64;
    const int  cbase = (fwd ? blk : blk - 64) * 16;
    const int  l  = threadIdx.x;
    const int  cl = l & 15;                // chain-in-group == MFMA col
    const int  g  = l >> 4;                // 4-lane group == row/k quarter
    const int  chain = cbase + cl;
    const float LOG2E = 1.44269504088896340736f;

    __shared__ float Elds[RING][4][64][4]; // 32 KB: [slot][m][lane][4]
    __shared__ int   Mlds[16][260];        // 16.6 KB, padded: bank-free reads

    const float* emln = emissions + (size_t)chain * SQ * NL + 4 * g; // lane E base
    const int*   mkc  = mask + (size_t)chain * SQ + (fwd ? 0 : 256);
    const int    bpa  = cl * 4;            // bpermute byte addr: lane cl (g==0)

    // ---- resident A fragments (one-time) ----
    h8 Afr[4][2];
#pragma unroll
    for (int m = 0; m < 4; ++m) {
#pragma unroll
        for (int ks = 0; ks < 2; ++ks) {
            i32x4 w;
#pragma unroll
            for (int ep = 0; ep < 4; ++ep) {
                const int e0 = 2*ep, e1 = 2*ep + 1;
                const int k0 = 32*ks + 16*(e0>>2) + 4*g + (e0&3);
                const int k1 = 32*ks + 16*(e1>>2) + 4*g + (e1&3);
                float v0, v1;
                if (fwd) { v0 = __expf(trans[k0*NL + (16*m + cl)]);   // ET^T
                           v1 = __expf(trans[k1*NL + (16*m + cl)]); }
                else     { v0 = __expf(trans[(16*m + cl)*NL + k0]);   // ET
                           v1 = __expf(trans[(16*m + cl)*NL + k1]); }
                w[ep] = pkf16(v0, v1);
            }
            Afr[m][ks] = __builtin_bit_cast(h8, w);
        }
    }

    // ---- mask preload to LDS (one-time; lane (cl,g) owns t in [64g,64g+64)) ----
#pragma unroll
    for (int kk = 0; kk < 16; ++kk) {
        const i32x4 v = *reinterpret_cast<const i32x4*>(mkc + 64*g + 4*kk);
        *reinterpret_cast<i32x4*>(&Mlds[cl][64*g + 4*kk]) = v;
    }

    // ---- state init (plain global loads; all drain before ring issues) ----
    const f32x4 zz = {0.f, 0.f, 0.f, 0.f};
    f32x4 pD[4];
    float basec = 0.f;
    int   esum  = 0;

    if (fwd) {
        f32x4 s0[4];
#pragma unroll
        for (int m = 0; m < 4; ++m) {
            const f32x4 st = *reinterpret_cast<const f32x4*>(start_t + 16*m + 4*g);
            const f32x4 e0 = *reinterpret_cast<const f32x4*>(emissions + (size_t)chain*SQ*NL + 16*m + 4*g);
            s0[m] = st + e0;
        }
        const int anci = __builtin_amdgcn_ds_bpermute(bpa, __float_as_int(s0[0][0]));
        const float anc = __int_as_float(anci);
        basec = anc * LOG2E;
#pragma unroll
        for (int m = 0; m < 4; ++m)
#pragma unroll
            for (int r = 0; r < 4; ++r)
                pD[m][r] = EXP2F((s0[m][r] - anc) * LOG2E);
    } else {
#pragma unroll
        for (int m = 0; m < 4; ++m) {
            const f32x4 ev = *reinterpret_cast<const f32x4*>(end_t + 16*m + 4*g);
#pragma unroll
            for (int r = 0; r < 4; ++r) pD[m][r] = __expf(ev[r]);
        }
        basec = 0.f;
    }

    // drain all prologue vmem so counted vmcnt starts from 0
    asm volatile("s_waitcnt vmcnt(0)" ::: "memory");
    __builtin_amdgcn_sched_barrier(0);

    // ---- step lambdas (round-9 verified math) ----
    auto stepF = [&](const f32x4 (&E)[4], int mm) {
        f32x4 ex[4];
#pragma unroll
        for (int m = 0; m < 4; ++m)
#pragma unroll
            for (int r = 0; r < 4; ++r) ex[m][r] = EXP2F(E[m][r] * LOG2E);
        const int anci = __builtin_amdgcn_ds_bpermute(bpa, __float_as_int(pD[0][0]));
        const unsigned u = (unsigned)anci;
        const int eb = (int)((u >> 23) & 0xffu);
        const float sc = __uint_as_float((unsigned)(251 - eb) << 23);  // 2^(124-eb)
        i32x4 w0, w1;
        w0[0] = pkf16(pD[0][0]*sc, pD[0][1]*sc); w0[1] = pkf16(pD[0][2]*sc, pD[0][3]*sc);
        w0[2] = pkf16(pD[1][0]*sc, pD[1][1]*sc); w0[3] = pkf16(pD[1][2]*sc, pD[1][3]*sc);
        w1[0] = pkf16(pD[2][0]*sc, pD[2][1]*sc); w1[1] = pkf16(pD[2][2]*sc, pD[2][3]*sc);
        w1[2] = pkf16(pD[3][0]*sc, pD[3][1]*sc); w1[3] = pkf16(pD[3][2]*sc, pD[3][3]*sc);
        const h8 B0 = __builtin_bit_cast(h8, w0);
        const h8 B1 = __builtin_bit_cast(h8, w1);
        f32x4 ac[4];
#pragma unroll
        for (int m = 0; m < 4; ++m) {
            ac[m] = MFMA16(Afr[m][0], B0, zz);
            ac[m] = MFMA16(Afr[m][1], B1, ac[m]);
        }
#pragma unroll
        for (int m = 0; m < 4; ++m)
#pragma unroll
            for (int r = 0; r < 4; ++r)
                pD[m][r] = mm ? (ex[m][r] * ac[m][r]) : pD[m][r];
        esum += mm ? (eb - 124) : 0;
    };

    auto stepB = [&](const f32x4 (&E)[4], int mm) {
        f32x4 scv[4];
#pragma unroll
        for (int m = 0; m < 4; ++m)
#pragma unroll
            for (int r = 0; r < 4; ++r)
                scv[m][r] = EXP2F(E[m][r] * LOG2E) * pD[m][r];
        const int anci = __builtin_amdgcn_ds_bpermute(bpa, __float_as_int(scv[0][0]));
        const unsigned u = (unsigned)anci;
        const int eb = (int)((u >> 23) & 0xffu);
        const float sc = __uint_as_float((unsigned)(251 - eb) << 23);
        i32x4 w0, w1;
        w0[0] = pkf16(scv[0][0]*sc, scv[0][1]*sc); w0[1] = pkf16(scv[0][2]*sc, scv[0][3]*sc);
        w0[2] = pkf16(scv[1][0]*sc, scv[1][1]*sc); w0[3] = pkf16(scv[1][2]*sc, scv[1][3]*sc);
        w1[0] = pkf16(scv[2][0]*sc, scv[2][1]*sc); w1[1] = pkf16(scv[2][2]*sc, scv[2][3]*sc);
        w1[2] = pkf16(scv[3][0]*sc, scv[3][1]*sc); w1[3] = pkf16(scv[3][2]*sc, scv[3][3]*sc);
        const h8 B0 = __builtin_bit_cast(h8, w0);
        const h8 B1 = __builtin_bit_cast(h8, w1);
        f32x4 ac[4];
#pragma unroll
        for (int m = 0; m < 4; ++m) {
            ac[m] = MFMA16(Afr[m][0], B0, zz);
            ac[m] = MFMA16(Afr[m][1], B1, ac[m]);
        }
#pragma unroll
        for (int m = 0; m < 4; ++m)
#pragma unroll
            for (int r = 0; r < 4; ++r)
                pD[m][r] = mm ? ac[m][r] : pD[m][r];
        esum += mm ? (eb - 124) : 0;
    };

    // issue 4 async loads for time-row t into ring slot
    auto issueE = [&](int slot, int t) {
#pragma unroll
        for (int m = 0; m < 4; ++m)
            gl_lds16(emln + (size_t)t * NL + 16*m, &Elds[slot][m][0][0]);
    };
    auto readE = [&](int slot, f32x4 (&E)[4]) {
#pragma unroll
        for (int m = 0; m < 4; ++m)
            E[m] = *reinterpret_cast<const f32x4*>(&Elds[slot][m][l][0]);
    };

    if (fwd) {
        for (int sp = 1; sp <= DEPTH; ++sp) issueE(sp & (RING-1), sp);
        asm volatile("s_waitcnt vmcnt(20)" ::: "memory");
        __builtin_amdgcn_sched_barrier(0);
        f32x4 Ec[4]; readE(1, Ec);

        for (int s = 1; s <= 255; ++s) {
            int tp = s + DEPTH; if (tp > 255) tp = 255;
            issueE((s + DEPTH) & (RING-1), tp);
            asm volatile("s_waitcnt vmcnt(20)" ::: "memory");
            __builtin_amdgcn_sched_barrier(0);
            f32x4 En[4]; readE((s + 1) & (RING-1), En);
            const int mm = Mlds[cl][s];
            stepF(Ec, mm);
#pragma unroll
            for (int m = 0; m < 4; ++m) Ec[m] = En[m];
        }
    } else {
        for (int ip = 0; ip < DEPTH; ++ip) issueE(ip & (RING-1), 511 - ip);
        asm volatile("s_waitcnt vmcnt(20)" ::: "memory");
        __builtin_amdgcn_sched_barrier(0);
        f32x4 Ec[4]; readE(0, Ec);

        for (int i = 0; i < 256; ++i) {
            const int t = 511 - i;
            int tq = t - DEPTH; if (tq < 256) tq = 256;
            issueE((i + DEPTH) & (RING-1), tq);
            asm volatile("s_waitcnt vmcnt(20)" ::: "memory");
            __builtin_amdgcn_sched_barrier(0);
            f32x4 En[4]; readE((i + 1) & (RING-1), En);
            const int mm = Mlds[cl][t - 256];
            stepB(Ec, mm);
#pragma unroll
            for (int m = 0; m < 4; ++m) Ec[m] = En[m];
        }
    }

    // write out: slot = chain (+BATCH for bwd); lane (cl,g) owns states 16m+4g+0..3
    const int slot = (fwd ? 0 : BATCH) + chain;
#pragma unroll
    for (int m = 0; m < 4; ++m)
        *reinterpret_cast<f32x4*>(ws_p + (size_t)slot*NL + 16*m + 4*g) = pD[m];
    if (g == 0) ws_c[slot] = basec + (float)esum;
}

// out[b] = ln2 * ( c2f + c2b + log2( sum_j pf[j] * pb[j] ) )
__global__ __launch_bounds__(64) void crf_combine(
    const float* __restrict__ ws_p, const float* __restrict__ ws_c,
    float* __restrict__ out)
{
    const int b = blockIdx.x;
    const int j = threadIdx.x;
    float v = ws_p[(size_t)b * NL + j] * ws_p[(size_t)(b + BATCH) * NL + j];
#pragma unroll
    for (int off = 32; off; off >>= 1) v += __shfl_xor(v, off);
    if (j == 0)
        out[b] = 0.69314718055994530942f *
                 (ws_c[b] + ws_c[b + BATCH] + LOG2F(v));
}

extern "C" void kernel_launch(void* const* d_in, const int* in_sizes, int n_in,
                              void* d_out, int out_size, void* d_ws, size_t ws_size,
                              hipStream_t stream) {
    const float* emissions = (const float*)d_in[0];
    const int*   mask      = (const int*)d_in[1];
    const float* trans     = (const float*)d_in[2];
    const float* start_t   = (const float*)d_in[3];
    const float* end_t     = (const float*)d_in[4];
    float* out = (float*)d_out;

    float* ws_p = (float*)d_ws;                    // 2*1024*64 floats
    float* ws_c = ws_p + 2 * BATCH * NL;           // 2*1024 floats

    crf_scan_mfma<<<128, NL, 0, stream>>>(emissions, mask, trans,
                                          start_t, end_t, ws_p, ws_c);
    crf_combine<<<BATCH, NL, 0, stream>>>(ws_p, ws_c, out);
}

// Round 5
// 381.591 us; speedup vs baseline: 1.0482x; 1.0482x over previous
//
#include <hip/hip_runtime.h>

#define NL 64
#define SQ 512
#define BATCH 1024
#define TMID 256
#define RING 8
#define DEPTH 6    // prefetch distance in steps; vmcnt wait = 4*(DEPTH-1) = 20

typedef __fp16   hf2   __attribute__((ext_vector_type(2)));
typedef _Float16 h8    __attribute__((ext_vector_type(8)));
typedef float    f32x4 __attribute__((ext_vector_type(4)));
typedef int      i32x4 __attribute__((ext_vector_type(4)));

#define EXP2F(x)  __builtin_amdgcn_exp2f(x)   // 2^x (v_exp_f32)
#define LOG2F(x)  __builtin_amdgcn_logf(x)    // log2 (v_log_f32)
#define MFMA16(a,b,c) __builtin_amdgcn_mfma_f32_16x16x32_f16((a),(b),(c),0,0,0)

static __device__ __forceinline__ int pkf16(float a, float b) {
    return __builtin_bit_cast(int, __builtin_amdgcn_cvt_pkrtz(a, b));
}
__device__ __forceinline__ float lane0_bcast(float v) {
    return __uint_as_float(__builtin_amdgcn_readfirstlane(__float_as_uint(v)));
}
__device__ __forceinline__ hf2 bc2(int pki, int lane) {
    int v = __builtin_amdgcn_readlane(pki, lane);
    return __builtin_bit_cast(hf2, v);
}

// async global->LDS, 16B per lane. LDS dest = wave-uniform base; HW writes
// lane l at base + l*16. Global src is per-lane.
static __device__ __forceinline__ void gl_lds16(const float* g, float* l) {
    __builtin_amdgcn_global_load_lds(
        (const __attribute__((address_space(1))) unsigned int*)g,
        (__attribute__((address_space(3))) unsigned int*)l, 16, 0, 0);
}

// ---------------------------------------------------------------------------
// Round-11. Root cause of rounds 9/10: the MFMA tile [16 chains][64 states]
// is a 16-way gather in the [B,S,L] layout (chains 128KB apart) -> every
// load/DMA instruction needs 16 scattered cache lines; with 1 wave/CU the
// exposed latency serializes the scan (round 10: 97% stall even L3-warm).
// Fix the LAYOUT: one-shot transpose pass emT[t][grp][m][lane][4] puts each
// wave-step tile contiguous (4KB) and ALREADY in D-fragment order. The scan
// keeps the round-4 ring skeleton, but global_load_lds now sees the
// canonical pattern (lane l -> base + 16*l, 1KB linear) and ds_read_b128
// stays conflict-free. Per-step sched_barrier walls removed (the "memory"
// clobber on the vmcnt asm already orders the LDS reads).
// emT needs 128MB of workspace; if ws_size is too small we fall back to the
// verified round-1 VALU kernel (103.7us), so allocation policy can't fail us.
// ---------------------------------------------------------------------------

// transpose: emT[((t*64+grp)*4+m)*256 + l*4 + r]
//              = em[(grp*16+(l&15))*SQ*NL + t*NL + 16m + 4*(l>>4) + r]
__global__ __launch_bounds__(256) void crf_transpose(
    const float* __restrict__ emissions, float* __restrict__ emT)
{
    const int blk = blockIdx.x;            // t*64 + grp
    const int t   = blk >> 6;
    const int grp = blk & 63;
    const int tid = threadIdx.x;           // m*64 + l
    const int m   = tid >> 6;
    const int l   = tid & 63;
    const int chain = grp * 16 + (l & 15);
    const f32x4 v = *reinterpret_cast<const f32x4*>(
        emissions + (size_t)chain * SQ * NL + (size_t)t * NL + 16*m + 4*(l >> 4));
    *reinterpret_cast<f32x4*>(emT + (size_t)blk * 1024 + tid * 4) = v;
}

__global__ __launch_bounds__(64, 1) void crf_scan_mfma(
    const float* __restrict__ emissions,   // [B, S, L] (t=0 init only)
    const float* __restrict__ emT,         // [512][64][4][64][4] transposed
    const int*   __restrict__ mask,        // [B, S]
    const float* __restrict__ trans,       // [L, L]
    const float* __restrict__ start_t,     // [L]
    const float* __restrict__ end_t,       // [L]
    float* __restrict__ ws_p,              // [2B][64]
    float* __restrict__ ws_c)              // [2B]
{
    const int  blk   = blockIdx.x;         // 0..127
    const bool fwd   = blk < 64;
    const int  grp   = fwd ? blk : blk - 64;
    const int  l  = threadIdx.x;
    const int  cl = l & 15;
    const int  g  = l >> 4;
    const int  chain = grp * 16 + cl;
    const float LOG2E = 1.44269504088896340736f;

    __shared__ float Elds[RING][4][64][4]; // 32 KB
    __shared__ int   Mlds[16][260];        // padded

    const int*   mkc = mask + (size_t)chain * SQ + (fwd ? 0 : 256);
    const int    bpa = cl * 4;

    // resident A fragments
    h8 Afr[4][2];
#pragma unroll
    for (int m = 0; m < 4; ++m) {
#pragma unroll
        for (int ks = 0; ks < 2; ++ks) {
            i32x4 w;
#pragma unroll
            for (int ep = 0; ep < 4; ++ep) {
                const int e0 = 2*ep, e1 = 2*ep + 1;
                const int k0 = 32*ks + 16*(e0>>2) + 4*g + (e0&3);
                const int k1 = 32*ks + 16*(e1>>2) + 4*g + (e1&3);
                float v0, v1;
                if (fwd) { v0 = __expf(trans[k0*NL + (16*m + cl)]);
                           v1 = __expf(trans[k1*NL + (16*m + cl)]); }
                else     { v0 = __expf(trans[(16*m + cl)*NL + k0]);
                           v1 = __expf(trans[(16*m + cl)*NL + k1]); }
                w[ep] = pkf16(v0, v1);
            }
            Afr[m][ks] = __builtin_bit_cast(h8, w);
        }
    }

    // mask preload (one-time)
#pragma unroll
    for (int kk = 0; kk < 16; ++kk) {
        const i32x4 v = *reinterpret_cast<const i32x4*>(mkc + 64*g + 4*kk);
        *reinterpret_cast<i32x4*>(&Mlds[cl][64*g + 4*kk]) = v;
    }

    const f32x4 zz = {0.f, 0.f, 0.f, 0.f};
    f32x4 pD[4];
    float basec = 0.f;
    int   esum  = 0;

    if (fwd) {
        f32x4 s0[4];
#pragma unroll
        for (int m = 0; m < 4; ++m) {
            const f32x4 st = *reinterpret_cast<const f32x4*>(start_t + 16*m + 4*g);
            const f32x4 e0 = *reinterpret_cast<const f32x4*>(
                emissions + (size_t)chain*SQ*NL + 16*m + 4*g);
            s0[m] = st + e0;
        }
        const int anci = __builtin_amdgcn_ds_bpermute(bpa, __float_as_int(s0[0][0]));
        const float anc = __int_as_float(anci);
        basec = anc * LOG2E;
#pragma unroll
        for (int m = 0; m < 4; ++m)
#pragma unroll
            for (int r = 0; r < 4; ++r)
                pD[m][r] = EXP2F((s0[m][r] - anc) * LOG2E);
    } else {
#pragma unroll
        for (int m = 0; m < 4; ++m) {
            const f32x4 ev = *reinterpret_cast<const f32x4*>(end_t + 16*m + 4*g);
#pragma unroll
            for (int r = 0; r < 4; ++r) pD[m][r] = __expf(ev[r]);
        }
        basec = 0.f;
    }

    asm volatile("s_waitcnt vmcnt(0)" ::: "memory");
    __builtin_amdgcn_sched_barrier(0);

    auto stepF = [&](const f32x4 (&E)[4], int mm) {
        f32x4 ex[4];
#pragma unroll
        for (int m = 0; m < 4; ++m)
#pragma unroll
            for (int r = 0; r < 4; ++r) ex[m][r] = EXP2F(E[m][r] * LOG2E);
        const int anci = __builtin_amdgcn_ds_bpermute(bpa, __float_as_int(pD[0][0]));
        const unsigned u = (unsigned)anci;
        const int eb = (int)((u >> 23) & 0xffu);
        const float sc = __uint_as_float((unsigned)(251 - eb) << 23);  // 2^(124-eb)
        i32x4 w0, w1;
        w0[0] = pkf16(pD[0][0]*sc, pD[0][1]*sc); w0[1] = pkf16(pD[0][2]*sc, pD[0][3]*sc);
        w0[2] = pkf16(pD[1][0]*sc, pD[1][1]*sc); w0[3] = pkf16(pD[1][2]*sc, pD[1][3]*sc);
        w1[0] = pkf16(pD[2][0]*sc, pD[2][1]*sc); w1[1] = pkf16(pD[2][2]*sc, pD[2][3]*sc);
        w1[2] = pkf16(pD[3][0]*sc, pD[3][1]*sc); w1[3] = pkf16(pD[3][2]*sc, pD[3][3]*sc);
        const h8 B0 = __builtin_bit_cast(h8, w0);
        const h8 B1 = __builtin_bit_cast(h8, w1);
        f32x4 ac[4];
#pragma unroll
        for (int m = 0; m < 4; ++m) {
            ac[m] = MFMA16(Afr[m][0], B0, zz);
            ac[m] = MFMA16(Afr[m][1], B1, ac[m]);
        }
#pragma unroll
        for (int m = 0; m < 4; ++m)
#pragma unroll
            for (int r = 0; r < 4; ++r)
                pD[m][r] = mm ? (ex[m][r] * ac[m][r]) : pD[m][r];
        esum += mm ? (eb - 124) : 0;
    };

    auto stepB = [&](const f32x4 (&E)[4], int mm) {
        f32x4 scv[4];
#pragma unroll
        for (int m = 0; m < 4; ++m)
#pragma unroll
            for (int r = 0; r < 4; ++r)
                scv[m][r] = EXP2F(E[m][r] * LOG2E) * pD[m][r];
        const int anci = __builtin_amdgcn_ds_bpermute(bpa, __float_as_int(scv[0][0]));
        const unsigned u = (unsigned)anci;
        const int eb = (int)((u >> 23) & 0xffu);
        const float sc = __uint_as_float((unsigned)(251 - eb) << 23);
        i32x4 w0, w1;
        w0[0] = pkf16(scv[0][0]*sc, scv[0][1]*sc); w0[1] = pkf16(scv[0][2]*sc, scv[0][3]*sc);
        w0[2] = pkf16(scv[1][0]*sc, scv[1][1]*sc); w0[3] = pkf16(scv[1][2]*sc, scv[1][3]*sc);
        w1[0] = pkf16(scv[2][0]*sc, scv[2][1]*sc); w1[1] = pkf16(scv[2][2]*sc, scv[2][3]*sc);
        w1[2] = pkf16(scv[3][0]*sc, scv[3][1]*sc); w1[3] = pkf16(scv[3][2]*sc, scv[3][3]*sc);
        const h8 B0 = __builtin_bit_cast(h8, w0);
        const h8 B1 = __builtin_bit_cast(h8, w1);
        f32x4 ac[4];
#pragma unroll
        for (int m = 0; m < 4; ++m) {
            ac[m] = MFMA16(Afr[m][0], B0, zz);
            ac[m] = MFMA16(Afr[m][1], B1, ac[m]);
        }
#pragma unroll
        for (int m = 0; m < 4; ++m)
#pragma unroll
            for (int r = 0; r < 4; ++r)
                pD[m][r] = mm ? ac[m][r] : pD[m][r];
        esum += mm ? (eb - 124) : 0;
    };

    // issue 4 coalesced DMA loads for time t: lane l reads 16B at base+16*l
    auto issueE = [&](int slot, int t) {
        const float* tb = emT + ((size_t)t * 64 + grp) * 1024 + 4 * l;
#pragma unroll
        for (int m = 0; m < 4; ++m)
            gl_lds16(tb + m * 256, &Elds[slot][m][0][0]);
    };
    auto readE = [&](int slot, f32x4 (&E)[4]) {
#pragma unroll
        for (int m = 0; m < 4; ++m)
            E[m] = *reinterpret_cast<const f32x4*>(&Elds[slot][m][l][0]);
    };

    if (fwd) {
        for (int sp = 1; sp <= DEPTH; ++sp) issueE(sp & (RING-1), sp);
        asm volatile("s_waitcnt vmcnt(20)" ::: "memory");
        f32x4 Ec[4]; readE(1, Ec);

        for (int s = 1; s <= 255; ++s) {
            int tp = s + DEPTH; if (tp > 255) tp = 255;
            issueE((s + DEPTH) & (RING-1), tp);
            asm volatile("s_waitcnt vmcnt(20)" ::: "memory");
            f32x4 En[4]; readE((s + 1) & (RING-1), En);
            const int mm = Mlds[cl][s];
            stepF(Ec, mm);
#pragma unroll
            for (int m = 0; m < 4; ++m) Ec[m] = En[m];
        }
    } else {
        for (int ip = 0; ip < DEPTH; ++ip) issueE(ip & (RING-1), 511 - ip);
        asm volatile("s_waitcnt vmcnt(20)" ::: "memory");
        f32x4 Ec[4]; readE(0, Ec);

        for (int i = 0; i < 256; ++i) {
            const int t = 511 - i;
            int tq = t - DEPTH; if (tq < 256) tq = 256;
            issueE((i + DEPTH) & (RING-1), tq);
            asm volatile("s_waitcnt vmcnt(20)" ::: "memory");
            f32x4 En[4]; readE((i + 1) & (RING-1), En);
            const int mm = Mlds[cl][t - 256];
            stepB(Ec, mm);
#pragma unroll
            for (int m = 0; m < 4; ++m) Ec[m] = En[m];
        }
    }

    const int slot = (fwd ? 0 : BATCH) + chain;
#pragma unroll
    for (int m = 0; m < 4; ++m)
        *reinterpret_cast<f32x4*>(ws_p + (size_t)slot*NL + 16*m + 4*g) = pD[m];
    if (g == 0) ws_c[slot] = basec + (float)esum;
}

// ---------------- legacy fallback (verified round-1 kernel, 103.7us) -------
__global__ __launch_bounds__(64, 2) void crf_scan_legacy(
    const float* __restrict__ emissions, const int* __restrict__ mask,
    const float* __restrict__ trans, const float* __restrict__ start_t,
    const float* __restrict__ end_t, float* __restrict__ ws_p,
    float* __restrict__ ws_c)
{
    const int  blk = blockIdx.x;
    const bool fwd = blk < BATCH;
    const int  b   = fwd ? blk : blk - BATCH;
    const int  j   = threadIdx.x;
    const float LOG2E = 1.44269504088896340736f;

    const float* em = emissions + (size_t)b * SQ * NL;
    const int*   mk = mask + (size_t)b * SQ;

    hf2 et2[NL / 2];
#pragma unroll
    for (int k = 0; k < NL / 2; ++k) {
        float e0, e1;
        if (fwd) { e0 = __expf(trans[(2*k + 0) * NL + j]);
                   e1 = __expf(trans[(2*k + 1) * NL + j]); }
        else     { e0 = __expf(trans[j * NL + (2*k + 0)]);
                   e1 = __expf(trans[j * NL + (2*k + 1)]); }
        et2[k] = __builtin_amdgcn_cvt_pkrtz(e0, e1);
    }

    auto matvec = [&](float xb) -> float {
        int nb = __builtin_amdgcn_update_dpp(0, __float_as_int(xb),
                                             0xB1, 0xF, 0xF, true);
        hf2 pk = __builtin_amdgcn_cvt_pkrtz(xb, __int_as_float(nb));
        int pki = __builtin_bit_cast(int, pk);
        float a0 = 0.f, a1 = 0.f, a2 = 0.f, a3 = 0.f;
        float a4 = 0.f, a5 = 0.f, a6 = 0.f, a7 = 0.f;
#pragma unroll
        for (int k = 0; k < 32; k += 8) {
            a0 = __builtin_amdgcn_fdot2(bc2(pki, 2*(k+0)), et2[k+0], a0, false);
            a1 = __builtin_amdgcn_fdot2(bc2(pki, 2*(k+1)), et2[k+1], a1, false);
            a2 = __builtin_amdgcn_fdot2(bc2(pki, 2*(k+2)), et2[k+2], a2, false);
            a3 = __builtin_amdgcn_fdot2(bc2(pki, 2*(k+3)), et2[k+3], a3, false);
            a4 = __builtin_amdgcn_fdot2(bc2(pki, 2*(k+4)), et2[k+4], a4, false);
            a5 = __builtin_amdgcn_fdot2(bc2(pki, 2*(k+5)), et2[k+5], a5, false);
            a6 = __builtin_amdgcn_fdot2(bc2(pki, 2*(k+6)), et2[k+6], a6, false);
            a7 = __builtin_amdgcn_fdot2(bc2(pki, 2*(k+7)), et2[k+7], a7, false);
        }
        return ((a0 + a1) + (a2 + a3)) + ((a4 + a5) + (a6 + a7));
    };

    float p, base;
    int   esum = 0;

    if (fwd) {
        float pe1 = em[1*NL + j], pe2 = em[2*NL + j], pe3 = em[3*NL + j];
        int   pm1 = mk[1], pm2 = mk[2], pm3 = mk[3];
        float r0 = em[ 4*NL + j], r1 = em[ 5*NL + j];
        float r2 = em[ 6*NL + j], r3 = em[ 7*NL + j];
        float r4 = em[ 8*NL + j], r5 = em[ 9*NL + j];
        float r6 = em[10*NL + j], r7 = em[11*NL + j];
        int4 M0 = *reinterpret_cast<const int4*>(mk + 4);
        int4 M1 = *reinterpret_cast<const int4*>(mk + 8);

        const float s0f = start_t[j] + em[j];
        const float C   = lane0_bcast(s0f);
        p = EXP2F((s0f - C) * LOG2E);  base = C * LOG2E;

        auto step = [&](float r, int m) {
            const float ex = EXP2F(r * LOG2E);
            const unsigned u = __builtin_amdgcn_readfirstlane(__float_as_uint(p));
            const int eb = (int)((u >> 23) & 0xffu);
            const float scale = __uint_as_float((unsigned)(251 - eb) << 23);
            const float mv = matvec(p * scale);
            if (m) { p = ex * mv; esum += eb - 124; }
        };

        step(pe1, pm1); step(pe2, pm2); step(pe3, pm3);
        for (int G = 0; G < 31; ++G) {
            const int t0 = 4 + 8 * G;
            const int t8 = t0 + 8;
            const int tA = (t0+12 > 255) ? 255 : t0+12;
            const int tB = (t0+13 > 255) ? 255 : t0+13;
            const int tC = (t0+14 > 255) ? 255 : t0+14;
            const int tD = (t0+15 > 255) ? 255 : t0+15;
            float n0 = em[(t8+0)*NL + j], n1 = em[(t8+1)*NL + j];
            float n2 = em[(t8+2)*NL + j], n3 = em[(t8+3)*NL + j];
            float n4 = em[tA*NL + j],     n5 = em[tB*NL + j];
            float n6 = em[tC*NL + j],     n7 = em[tD*NL + j];
            int4 nM0 = *reinterpret_cast<const int4*>(mk + t8);
            const int tm1 = (t0+12 > 252) ? 252 : t0+12;
            int4 nM1 = *reinterpret_cast<const int4*>(mk + tm1);

            step(r0, M0.x); step(r1, M0.y); step(r2, M0.z); step(r3, M0.w);
            step(r4, M1.x); step(r5, M1.y); step(r6, M1.z); step(r7, M1.w);

            r0=n0; r1=n1; r2=n2; r3=n3; r4=n4; r5=n5; r6=n6; r7=n7;
            M0=nM0; M1=nM1;
        }
        step(r0, M0.x); step(r1, M0.y); step(r2, M0.z); step(r3, M0.w);
    } else {
        float r0 = em[511*NL + j], r1 = em[510*NL + j];
        float r2 = em[509*NL + j], r3 = em[508*NL + j];
        float r4 = em[507*NL + j], r5 = em[506*NL + j];
        float r6 = em[505*NL + j], r7 = em[504*NL + j];
        int4 Ma = *reinterpret_cast<const int4*>(mk + 508);
        int4 Mb = *reinterpret_cast<const int4*>(mk + 504);

        p = __expf(end_t[j]);  base = 0.f;

        auto step = [&](float r, int m) {
            const float ex = EXP2F(r * LOG2E);
            const float sc = ex * p;
            const unsigned u = __builtin_amdgcn_readfirstlane(__float_as_uint(sc));
            const int eb = (int)((u >> 23) & 0xffu);
            const float scale = __uint_as_float((unsigned)(251 - eb) << 23);
            const float mv = matvec(sc * scale);
            if (m) { p = mv; esum += eb - 124; }
        };

        for (int G = 0; G < 32; ++G) {
            const int t0 = 511 - 8 * G;
            const int tb = t0 - 8;
            const int te0 = (tb-0 < 256) ? 256 : tb-0;
            const int te1 = (tb-1 < 256) ? 256 : tb-1;
            const int te2 = (tb-2 < 256) ? 256 : tb-2;
            const int te3 = (tb-3 < 256) ? 256 : tb-3;
            const int te4 = (tb-4 < 256) ? 256 : tb-4;
            const int te5 = (tb-5 < 256) ? 256 : tb-5;
            const int te6 = (tb-6 < 256) ? 256 : tb-6;
            const int te7 = (tb-7 < 256) ? 256 : tb-7;
            float n0 = em[te0*NL + j], n1 = em[te1*NL + j];
            float n2 = em[te2*NL + j], n3 = em[te3*NL + j];
            float n4 = em[te4*NL + j], n5 = em[te5*NL + j];
            float n6 = em[te6*NL + j], n7 = em[te7*NL + j];
            const int ta  = (tb-3 < 256) ? 256 : tb-3;
            const int tbb = (tb-7 < 256) ? 256 : tb-7;
            int4 nMa = *reinterpret_cast<const int4*>(mk + ta);
            int4 nMb = *reinterpret_cast<const int4*>(mk + tbb);

            step(r0, Ma.w); step(r1, Ma.z); step(r2, Ma.y); step(r3, Ma.x);
            step(r4, Mb.w); step(r5, Mb.z); step(r6, Mb.y); step(r7, Mb.x);

            r0=n0; r1=n1; r2=n2; r3=n3; r4=n4; r5=n5; r6=n6; r7=n7;
            Ma=nMa; Mb=nMb;
        }
    }

    ws_p[(size_t)blk * NL + j] = p;
    if (j == 0) ws_c[blk] = base + (float)esum;
}

// out[b] = ln2 * ( c2f + c2b + log2( sum_j pf[j] * pb[j] ) )
__global__ __launch_bounds__(64) void crf_combine(
    const float* __restrict__ ws_p, const float* __restrict__ ws_c,
    float* __restrict__ out)
{
    const int b = blockIdx.x;
    const int j = threadIdx.x;
    float v = ws_p[(size_t)b * NL + j] * ws_p[(size_t)(b + BATCH) * NL + j];
#pragma unroll
    for (int off = 32; off; off >>= 1) v += __shfl_xor(v, off);
    if (j == 0)
        out[b] = 0.69314718055994530942f *
                 (ws_c[b] + ws_c[b + BATCH] + LOG2F(v));
}

extern "C" void kernel_launch(void* const* d_in, const int* in_sizes, int n_in,
                              void* d_out, int out_size, void* d_ws, size_t ws_size,
                              hipStream_t stream) {
    const float* emissions = (const float*)d_in[0];
    const int*   mask      = (const int*)d_in[1];
    const float* trans     = (const float*)d_in[2];
    const float* start_t   = (const float*)d_in[3];
    const float* end_t     = (const float*)d_in[4];
    float* out = (float*)d_out;

    float* ws_p = (float*)d_ws;                    // 2*1024*64 floats
    float* ws_c = ws_p + 2 * BATCH * NL;           // 2*1024 floats
    float* emT  = ws_c + 2 * BATCH;                // 512*64*1024 floats (128MB)

    const size_t need = ((size_t)2*BATCH*NL + 2*BATCH + (size_t)SQ*64*1024) * 4;

    if (ws_size >= need) {
        crf_transpose<<<SQ * 64, 256, 0, stream>>>(emissions, emT);
        crf_scan_mfma<<<128, NL, 0, stream>>>(emissions, emT, mask, trans,
                                              start_t, end_t, ws_p, ws_c);
    } else {
        crf_scan_legacy<<<2 * BATCH, NL, 0, stream>>>(emissions, mask, trans,
                                                      start_t, end_t, ws_p, ws_c);
    }
    crf_combine<<<BATCH, NL, 0, stream>>>(ws_p, ws_c, out);
}

// Round 6
// 257.153 us; speedup vs baseline: 1.5554x; 1.4839x over previous
//
#include <hip/hip_runtime.h>

#define NL 64
#define SQ 512
#define BATCH 1024

typedef _Float16 h8    __attribute__((ext_vector_type(8)));
typedef float    f32x4 __attribute__((ext_vector_type(4)));
typedef int      i32x4 __attribute__((ext_vector_type(4)));

#define EXP2F(x)  __builtin_amdgcn_exp2f(x)   // 2^x (v_exp_f32)
#define LOG2F(x)  __builtin_amdgcn_logf(x)    // log2 (v_log_f32)
#define MFMA16(a,b,c) __builtin_amdgcn_mfma_f32_16x16x32_f16((a),(b),(c),0,0,0)

static __device__ __forceinline__ int pkf16(float a, float b) {
    return __builtin_bit_cast(int, __builtin_amdgcn_cvt_pkrtz(a, b));
}

// ---------------------------------------------------------------------------
// Round-12. Rounds 10/11 showed global_load_lds -> ds_read serializes (the
// compiler can't prove non-aliasing of the DMA'd LDS, so every step pays a
// full memory round trip: 1470 cyc/step even L3-warm). Fix: no LDS-DMA, no
// transpose pass. The scan stages its own tiles:
//   - plain coalesced global_load_dwordx4 into REGISTERS: one inst = one
//     chain's contiguous 4-row (1KB) span, lane l takes bytes 16l..16l+15.
//   - 2-set ping-pong register FIFO (16 f32x4 per set); loads for block B+3
//     issued during block B, ds_written during B+1, ds_read during B+2.
//     All waits are compiler-counted vmcnt on register defs (the mechanism
//     that actually works), distances = 4 steps (~1200cyc) per hop.
//   - 3-slot LDS ring [slot][4 rows][1024 floats]; XOR swizzle
//     chunk' = chunk ^ ((chunk>>4)&7) on 16B chunks makes BOTH the
//     column-ish writes and the fragment reads hit all 8 bank groups
//     (b128 8-cyc floor). Verified element-wise:
//     write: inst c, lane l -> row=l>>4, chunk=16*(l&15)+c, xor l&7
//     read : lane l', m     -> row=r,    chunk=64m+l',      xor (4m+l'>>4)&7
//     (identical involution since (l&15)=4m+g' on the write side).
// Emissions are read exactly once (128MB), masks once. fwd runs t=0 as a
// masked no-op step so all 64 blocks are uniform 4-step blocks.
// Step math = round-5 verified stepF/stepB (exponent-bit renorm, f16 MFMA).
// ---------------------------------------------------------------------------
__global__ __launch_bounds__(64, 1) void crf_scan_mfma(
    const float* __restrict__ emissions,   // [B, S, L]
    const int*   __restrict__ mask,        // [B, S]
    const float* __restrict__ trans,       // [L, L]
    const float* __restrict__ start_t,     // [L]
    const float* __restrict__ end_t,       // [L]
    float* __restrict__ ws_p,              // [2B][64]
    float* __restrict__ ws_c)              // [2B]
{
    const int  blk   = blockIdx.x;         // 0..127
    const bool fwd   = blk < 64;
    const int  grp   = fwd ? blk : blk - 64;
    const int  l  = threadIdx.x;
    const int  cl = l & 15;
    const int  g  = l >> 4;
    const int  chain = grp * 16 + cl;
    const float LOG2E = 1.44269504088896340736f;

    __shared__ f32x4 Eldsv[3 * 4 * 256];   // 48 KB: 3 slots x 4 rows x 4KB
    __shared__ int   Mlds[16][260];        // padded
    char* EB = (char*)Eldsv;

    const float* emg = emissions + (size_t)grp * 16 * SQ * NL;  // group base
    const int*   mkc = mask + (size_t)chain * SQ + (fwd ? 0 : 256);
    const int    bpa = cl * 4;

    // ---- resident A fragments (round-5 verified) ----
    h8 Afr[4][2];
#pragma unroll
    for (int m = 0; m < 4; ++m) {
#pragma unroll
        for (int ks = 0; ks < 2; ++ks) {
            i32x4 w;
#pragma unroll
            for (int ep = 0; ep < 4; ++ep) {
                const int e0 = 2*ep, e1 = 2*ep + 1;
                const int k0 = 32*ks + 16*(e0>>2) + 4*g + (e0&3);
                const int k1 = 32*ks + 16*(e1>>2) + 4*g + (e1&3);
                float v0, v1;
                if (fwd) { v0 = __expf(trans[k0*NL + (16*m + cl)]);
                           v1 = __expf(trans[k1*NL + (16*m + cl)]); }
                else     { v0 = __expf(trans[(16*m + cl)*NL + k0]);
                           v1 = __expf(trans[(16*m + cl)*NL + k1]); }
                w[ep] = pkf16(v0, v1);
            }
            Afr[m][ks] = __builtin_bit_cast(h8, w);
        }
    }

    // ---- mask preload (round-5 verified) + fwd t=0 no-op patch ----
#pragma unroll
    for (int kk = 0; kk < 16; ++kk) {
        const i32x4 v = *reinterpret_cast<const i32x4*>(mkc + 64*g + 4*kk);
        *reinterpret_cast<i32x4*>(&Mlds[cl][64*g + 4*kk]) = v;
    }
    if (fwd && g == 0) Mlds[cl][0] = 0;    // t=0 step is identity

    // ---- state init (round-5 verified) ----
    const f32x4 zz = {0.f, 0.f, 0.f, 0.f};
    f32x4 pD[4];
    float basec = 0.f;
    int   esum  = 0;

    if (fwd) {
        f32x4 s0[4];
#pragma unroll
        for (int m = 0; m < 4; ++m) {
            const f32x4 st = *reinterpret_cast<const f32x4*>(start_t + 16*m + 4*g);
            const f32x4 e0 = *reinterpret_cast<const f32x4*>(
                emissions + (size_t)chain*SQ*NL + 16*m + 4*g);
            s0[m] = st + e0;
        }
        const int anci = __builtin_amdgcn_ds_bpermute(bpa, __float_as_int(s0[0][0]));
        const float anc = __int_as_float(anci);
        basec = anc * LOG2E;
#pragma unroll
        for (int m = 0; m < 4; ++m)
#pragma unroll
            for (int r = 0; r < 4; ++r)
                pD[m][r] = EXP2F((s0[m][r] - anc) * LOG2E);
    } else {
#pragma unroll
        for (int m = 0; m < 4; ++m) {
            const f32x4 ev = *reinterpret_cast<const f32x4*>(end_t + 16*m + 4*g);
#pragma unroll
            for (int r = 0; r < 4; ++r) pD[m][r] = __expf(ev[r]);
        }
        basec = 0.f;
    }

    // ---- step lambdas (round-5 verified math) ----
    f32x4 Ecur[4];

    auto stepF = [&](int mm) {
        f32x4 ex[4];
#pragma unroll
        for (int m = 0; m < 4; ++m)
#pragma unroll
            for (int r = 0; r < 4; ++r) ex[m][r] = EXP2F(Ecur[m][r] * LOG2E);
        const int anci = __builtin_amdgcn_ds_bpermute(bpa, __float_as_int(pD[0][0]));
        const unsigned u = (unsigned)anci;
        const int eb = (int)((u >> 23) & 0xffu);
        const float sc = __uint_as_float((unsigned)(251 - eb) << 23);  // 2^(124-eb)
        i32x4 w0, w1;
        w0[0] = pkf16(pD[0][0]*sc, pD[0][1]*sc); w0[1] = pkf16(pD[0][2]*sc, pD[0][3]*sc);
        w0[2] = pkf16(pD[1][0]*sc, pD[1][1]*sc); w0[3] = pkf16(pD[1][2]*sc, pD[1][3]*sc);
        w1[0] = pkf16(pD[2][0]*sc, pD[2][1]*sc); w1[1] = pkf16(pD[2][2]*sc, pD[2][3]*sc);
        w1[2] = pkf16(pD[3][0]*sc, pD[3][1]*sc); w1[3] = pkf16(pD[3][2]*sc, pD[3][3]*sc);
        const h8 B0 = __builtin_bit_cast(h8, w0);
        const h8 B1 = __builtin_bit_cast(h8, w1);
        f32x4 ac[4];
#pragma unroll
        for (int m = 0; m < 4; ++m) {
            ac[m] = MFMA16(Afr[m][0], B0, zz);
            ac[m] = MFMA16(Afr[m][1], B1, ac[m]);
        }
#pragma unroll
        for (int m = 0; m < 4; ++m)
#pragma unroll
            for (int r = 0; r < 4; ++r)
                pD[m][r] = mm ? (ex[m][r] * ac[m][r]) : pD[m][r];
        esum += mm ? (eb - 124) : 0;
    };

    auto stepB = [&](int mm) {
        f32x4 scv[4];
#pragma unroll
        for (int m = 0; m < 4; ++m)
#pragma unroll
            for (int r = 0; r < 4; ++r)
                scv[m][r] = EXP2F(Ecur[m][r] * LOG2E) * pD[m][r];
        const int anci = __builtin_amdgcn_ds_bpermute(bpa, __float_as_int(scv[0][0]));
        const unsigned u = (unsigned)anci;
        const int eb = (int)((u >> 23) & 0xffu);
        const float sc = __uint_as_float((unsigned)(251 - eb) << 23);
        i32x4 w0, w1;
        w0[0] = pkf16(scv[0][0]*sc, scv[0][1]*sc); w0[1] = pkf16(scv[0][2]*sc, scv[0][3]*sc);
        w0[2] = pkf16(scv[1][0]*sc, scv[1][1]*sc); w0[3] = pkf16(scv[1][2]*sc, scv[1][3]*sc);
        w1[0] = pkf16(scv[2][0]*sc, scv[2][1]*sc); w1[1] = pkf16(scv[2][2]*sc, scv[2][3]*sc);
        w1[2] = pkf16(scv[3][0]*sc, scv[3][1]*sc); w1[3] = pkf16(scv[3][2]*sc, scv[3][3]*sc);
        const h8 B0 = __builtin_bit_cast(h8, w0);
        const h8 B1 = __builtin_bit_cast(h8, w1);
        f32x4 ac[4];
#pragma unroll
        for (int m = 0; m < 4; ++m) {
            ac[m] = MFMA16(Afr[m][0], B0, zz);
            ac[m] = MFMA16(Afr[m][1], B1, ac[m]);
        }
#pragma unroll
        for (int m = 0; m < 4; ++m)
#pragma unroll
            for (int r = 0; r < 4; ++r)
                pD[m][r] = mm ? ac[m][r] : pD[m][r];
        esum += mm ? (eb - 124) : 0;
    };

    // ---- staging helpers ----
    const int l7 = l & 7;
    const int wb = ((l >> 4) << 12) + ((l & 15) << 8);  // row*4096 + 16*(l&15)*16
    int pbA[4];
#pragma unroll
    for (int m = 0; m < 4; ++m)
        pbA[m] = (((m << 6) + l) ^ ((4*m + (l >> 4)) & 7)) << 4;

    auto ldRow = [&](int slot, int row) {
        char* base = EB + slot * 16384 + row * 4096;
#pragma unroll
        for (int m = 0; m < 4; ++m)
            Ecur[m] = *(const f32x4*)(base + pbA[m]);
    };
    auto ldRowN = [&](int slot, int row, f32x4 (&E)[4]) {
        char* base = EB + slot * 16384 + row * 4096;
#pragma unroll
        for (int m = 0; m < 4; ++m)
            E[m] = *(const f32x4*)(base + pbA[m]);
    };
    auto gload = [&](int c, int rb) -> f32x4 {
        return *(const f32x4*)(emg + (size_t)c * SQ * NL + (size_t)rb * NL + 4 * l);
    };
    auto wInst = [&](int slot, int c, const f32x4& v) {
        *(f32x4*)(EB + slot * 16384 + wb + ((c ^ l7) << 4)) = v;
    };

    auto advs = [](int s) { return s == 2 ? 0 : s + 1; };

    f32x4 set0[16], set1[16];

    if (fwd) {
        auto doBlk = [&](f32x4 (&Lw)[16], f32x4 (&Lo)[16], int B, int sR, int sW) {
            const int bn = (B + 3 > 63) ? 63 : B + 3;
            const int rbN = 4 * bn;
#pragma unroll
            for (int u = 0; u < 4; ++u) {
                f32x4 En[4];
                if (u < 3) ldRowN(sR, u + 1, En);
                else       ldRowN(advs(sR), 0, En);
#pragma unroll
                for (int k = 0; k < 4; ++k) {
                    wInst(sW, 4*u + k, Lw[4*u + k]);
                    Lo[4*u + k] = gload(4*u + k, rbN);
                }
                const int mm = Mlds[cl][4*B + u];
                stepF(mm);
#pragma unroll
                for (int m = 0; m < 4; ++m) Ecur[m] = En[m];
            }
        };

        // prologue: blocks 0,1 staged; block 2 in flight
#pragma unroll
        for (int c = 0; c < 16; ++c) set0[c] = gload(c, 0);
#pragma unroll
        for (int c = 0; c < 16; ++c) wInst(0, c, set0[c]);
#pragma unroll
        for (int c = 0; c < 16; ++c) set1[c] = gload(c, 4);
#pragma unroll
        for (int c = 0; c < 16; ++c) wInst(1, c, set1[c]);
#pragma unroll
        for (int c = 0; c < 16; ++c) set0[c] = gload(c, 8);
        ldRow(0, 0);

        int sR = 0, sW = 2;
        for (int it = 0; it < 32; ++it) {
            doBlk(set0, set1, 2*it,     sR, sW); sR = advs(sR); sW = advs(sW);
            doBlk(set1, set0, 2*it + 1, sR, sW); sR = advs(sR); sW = advs(sW);
        }
    } else {
        auto doBlk = [&](f32x4 (&Lw)[16], f32x4 (&Lo)[16], int B, int sR, int sW) {
            const int bn = (B + 3 > 63) ? 63 : B + 3;
            const int rbN = 508 - 4 * bn;
#pragma unroll
            for (int u = 0; u < 4; ++u) {
                f32x4 En[4];
                if (u < 3) ldRowN(sR, 2 - u, En);      // next step's row = 3-(u+1)
                else       ldRowN(advs(sR), 3, En);
#pragma unroll
                for (int k = 0; k < 4; ++k) {
                    wInst(sW, 4*u + k, Lw[4*u + k]);
                    Lo[4*u + k] = gload(4*u + k, rbN);
                }
                const int mm = Mlds[cl][255 - 4*B - u];   // t = 511-4B-u
                stepB(mm);
#pragma unroll
                for (int m = 0; m < 4; ++m) Ecur[m] = En[m];
            }
        };

        // prologue: block0 rows 508..511, block1 504..507, block2 500..503
#pragma unroll
        for (int c = 0; c < 16; ++c) set0[c] = gload(c, 508);
#pragma unroll
        for (int c = 0; c < 16; ++c) wInst(0, c, set0[c]);
#pragma unroll
        for (int c = 0; c < 16; ++c) set1[c] = gload(c, 504);
#pragma unroll
        for (int c = 0; c < 16; ++c) wInst(1, c, set1[c]);
#pragma unroll
        for (int c = 0; c < 16; ++c) set0[c] = gload(c, 500);
        ldRow(0, 3);

        int sR = 0, sW = 2;
        for (int it = 0; it < 32; ++it) {
            doBlk(set0, set1, 2*it,     sR, sW); sR = advs(sR); sW = advs(sW);
            doBlk(set1, set0, 2*it + 1, sR, sW); sR = advs(sR); sW = advs(sW);
        }
    }

    // ---- write out (round-5 verified) ----
    const int slot = (fwd ? 0 : BATCH) + chain;
#pragma unroll
    for (int m = 0; m < 4; ++m)
        *reinterpret_cast<f32x4*>(ws_p + (size_t)slot*NL + 16*m + 4*g) = pD[m];
    if (g == 0) ws_c[slot] = basec + (float)esum;
}

// out[b] = ln2 * ( c2f + c2b + log2( sum_j pf[j] * pb[j] ) )
__global__ __launch_bounds__(64) void crf_combine(
    const float* __restrict__ ws_p, const float* __restrict__ ws_c,
    float* __restrict__ out)
{
    const int b = blockIdx.x;
    const int j = threadIdx.x;
    float v = ws_p[(size_t)b * NL + j] * ws_p[(size_t)(b + BATCH) * NL + j];
#pragma unroll
    for (int off = 32; off; off >>= 1) v += __shfl_xor(v, off);
    if (j == 0)
        out[b] = 0.69314718055994530942f *
                 (ws_c[b] + ws_c[b + BATCH] + LOG2F(v));
}

extern "C" void kernel_launch(void* const* d_in, const int* in_sizes, int n_in,
                              void* d_out, int out_size, void* d_ws, size_t ws_size,
                              hipStream_t stream) {
    const float* emissions = (const float*)d_in[0];
    const int*   mask      = (const int*)d_in[1];
    const float* trans     = (const float*)d_in[2];
    const float* start_t   = (const float*)d_in[3];
    const float* end_t     = (const float*)d_in[4];
    float* out = (float*)d_out;

    float* ws_p = (float*)d_ws;                    // 2*1024*64 floats
    float* ws_c = ws_p + 2 * BATCH * NL;           // 2*1024 floats

    crf_scan_mfma<<<128, NL, 0, stream>>>(emissions, mask, trans,
                                          start_t, end_t, ws_p, ws_c);
    crf_combine<<<BATCH, NL, 0, stream>>>(ws_p, ws_c, out);
}